// Round 5
// baseline (249.762 us; speedup 1.0000x reference)
//
#include <hip/hip_runtime.h>

#define EPB     64
#define E_TOTAL 262144
#define NPROBE  100000
#define N_ATOMS 20000
#define NTAB    4096         // W-table intervals over dist in [0,4); rows = NTAB+1

// LDS layout (main), short indices; total 35,840 B -> 4 blocks/CU
#define ASTR   136           // row stride: 272 B = 16 B * 17 -> 2-way (free) banks
#define A2_O   0             // A2 (then G) region [0, 8704)
#define S_O    8704          // state S region    [8704, 17408)
#define MPT_O  17408         // mpart: 256 floats (512 shorts)
#define LDS_SH 17920

// workspace layout (shorts)
#define WS1_O  0             // w_s1^T bf16: 128 x 384 ([n][k])
#define WS2_O  49152         // w_s2^T bf16: 128 x 128
#define WO1_O  65536         // w_o1^T bf16: 64 x 128
#define WT_TOT 73728
#define PQ_O   73728         // PQ[a][512] bf16: [P | Q0 | Q1 | Q2]
#define PQ_SH  (N_ATOMS * 512)
#define WTAB_OFF_B ((PQ_O + PQ_SH) * 2)   // byte offset of f32 wtab[NTAB+1][128]

typedef __attribute__((ext_vector_type(8))) short          short8;
typedef __attribute__((ext_vector_type(8))) unsigned short ushort8;
typedef __attribute__((ext_vector_type(4))) float          floatx4;

#define MFMA16(a, b, c) __builtin_amdgcn_mfma_f32_16x16x32_bf16((a), (b), (c), 0, 0, 0)

__device__ __forceinline__ short f2bf(float x) {            // RNE (prep only)
    unsigned u = __builtin_bit_cast(unsigned, x);
    u = (u + 0x7FFFu + ((u >> 16) & 1u)) >> 16;
    return (short)(unsigned short)u;
}
__device__ __forceinline__ unsigned pk2(float lo, float hi) {   // {bf16(hi)|bf16(lo)} trunc
    return __builtin_amdgcn_perm(__builtin_bit_cast(unsigned, hi),
                                 __builtin_bit_cast(unsigned, lo), 0x07060302u);
}
__device__ __forceinline__ float bf2f(unsigned short u) {
    return __builtin_bit_cast(float, ((unsigned)u) << 16);
}
__device__ __forceinline__ float silu_f(float x) { return x / (1.0f + __expf(-x)); }

struct F8 { float v[8]; };
__device__ __forceinline__ F8 ld8(const float* __restrict__ p) {
    F8 r;
    const float4 a = *(const float4*)p;
    const float4 b = *(const float4*)(p + 4);
    r.v[0] = a.x; r.v[1] = a.y; r.v[2] = a.z; r.v[3] = a.w;
    r.v[4] = b.x; r.v[5] = b.y; r.v[6] = b.z; r.v[7] = b.w;
    return r;
}

// prep 1: out init + weight transpose -> bf16 [n][k] (w_s1, w_s2, w_o1)
__global__ void cfr_prep_w(const float* __restrict__ w_s1, const float* __restrict__ w_s2,
                           const float* __restrict__ w_o1,
                           const float* __restrict__ fb, float* __restrict__ out,
                           unsigned short* __restrict__ wt) {
    int i = blockIdx.x * 256 + threadIdx.x;
    if (i < NPROBE) out[i] = fb[0];
    if (i < WT_TOT) {
        float v;
        if (i < WS2_O)      { int n = i / 384, k = i - n * 384;          v = w_s1[k * 128 + n]; }
        else if (i < WO1_O) { int j = i - WS2_O, n = j >> 7, k = j & 127; v = w_s2[k * 128 + n]; }
        else                { int j = i - WO1_O, n = j >> 7, k = j & 127; v = w_o1[k * 64 + n]; }
        wt[i] = (unsigned short)f2bf(v);
    }
}

// prep 2: W(dist) lookup table. One block per table row; thread = feature col.
// wtab[r][c] = (silu(e_pi(d_r) @ w_f1 + b_f1) @ w_f2 + b_f2)[c], d_r = r/1024.
__global__ __launch_bounds__(128) void cfr_prep_wtab(
    const float* __restrict__ w_f1, const float* __restrict__ b_f1,
    const float* __restrict__ w_f2, const float* __restrict__ b_f2,
    float* __restrict__ wtab)
{
    __shared__ float ep[32];
    __shared__ float f1s[128];
    const int t = threadIdx.x, row = blockIdx.x;
    float d = fmaxf(row * (4.0f / NTAB), 1e-4f);
    if (t < 32) ep[t] = sinf(d * (t + 1) * 0.7853981633974483f) / d;
    __syncthreads();
    float f1 = b_f1[t];
#pragma unroll
    for (int k = 0; k < 32; ++k) f1 = fmaf(ep[k], w_f1[k * 128 + t], f1);
    f1s[t] = silu_f(f1);
    __syncthreads();
    float w = b_f2[t];
    for (int k = 0; k < 128; ++k) w = fmaf(f1s[k], w_f2[k * 128 + t], w);
    wtab[row * 128 + t] = w;
}

// prep 3: per-atom P = [S|n]@w_s1[0:256] + b_s1 and Q_d = V_d@w_s1[256:384], bf16.
// 32 atoms/block, 43 KB LDS -> 3 blocks/CU.
__global__ __launch_bounds__(256, 3) void cfr_prep_pq(
    const float* __restrict__ S, const float* __restrict__ V,
    const float* __restrict__ b_s1,
    const unsigned short* __restrict__ wt, unsigned short* __restrict__ pq)
{
    __shared__ __align__(16) unsigned short bufH[32 * 264];   // [S|n], stride 264
    __shared__ __align__(16) unsigned short bufV[96 * 136];   // rows (d*32 + a_local)

    const int t    = threadIdx.x;
    const int a0   = blockIdx.x * 32;
    const int wave = t >> 6;
    const int lane = t & 63;
    const int q    = lane >> 4;
    const int c16  = lane & 15;

#pragma unroll
    for (int it = 0; it < 2; ++it) {
        int idx = it * 256 + t;
        int al = idx >> 4, f8 = (idx & 15) * 8;
        int a = a0 + al;
        ushort8 sS, sN, s0, s1, s2;
        if (a < N_ATOMS) {
            F8 s  = ld8(S + a * 128 + f8);
            F8 v0 = ld8(V + a * 384 + f8);
            F8 v1 = ld8(V + a * 384 + 128 + f8);
            F8 v2 = ld8(V + a * 384 + 256 + f8);
#pragma unroll
            for (int j = 0; j < 8; ++j) {
                sS[j] = (unsigned short)f2bf(s.v[j]);
                sN[j] = (unsigned short)f2bf(sqrtf(v0.v[j]*v0.v[j] + v1.v[j]*v1.v[j] + v2.v[j]*v2.v[j] + 1e-8f));
                s0[j] = (unsigned short)f2bf(v0.v[j]);
                s1[j] = (unsigned short)f2bf(v1.v[j]);
                s2[j] = (unsigned short)f2bf(v2.v[j]);
            }
        } else {
#pragma unroll
            for (int j = 0; j < 8; ++j) { sS[j]=0; sN[j]=0; s0[j]=0; s1[j]=0; s2[j]=0; }
        }
        *(ushort8*)&bufH[al * 264 + f8]        = sS;
        *(ushort8*)&bufH[al * 264 + 128 + f8]  = sN;
        *(ushort8*)&bufV[al * 136 + f8]        = s0;
        *(ushort8*)&bufV[(32 + al) * 136 + f8] = s1;
        *(ushort8*)&bufV[(64 + al) * 136 + f8] = s2;
    }
    __syncthreads();

    const floatx4 zero4 = {0.f, 0.f, 0.f, 0.f};
    float bs1c[2];
#pragma unroll
    for (int ni = 0; ni < 2; ++ni) bs1c[ni] = b_s1[wave * 32 + ni * 16 + c16];

    // P = [S|n] @ w_s1[0:256]
    {
        floatx4 pacc[2][2];
#pragma unroll
        for (int mi = 0; mi < 2; ++mi) { pacc[mi][0] = zero4; pacc[mi][1] = zero4; }
#pragma unroll
        for (int kk = 0; kk < 8; ++kk) {
            short8 bfr[2], af[2];
#pragma unroll
            for (int ni = 0; ni < 2; ++ni) {
                int n = wave * 32 + ni * 16 + c16;
                bfr[ni] = *(const short8*)&wt[WS1_O + n * 384 + kk * 32 + q * 8];
            }
#pragma unroll
            for (int mi = 0; mi < 2; ++mi)
                af[mi] = *(const short8*)&bufH[(mi * 16 + c16) * 264 + kk * 32 + q * 8];
#pragma unroll
            for (int mi = 0; mi < 2; ++mi)
#pragma unroll
                for (int ni = 0; ni < 2; ++ni)
                    pacc[mi][ni] = MFMA16(af[mi], bfr[ni], pacc[mi][ni]);
        }
#pragma unroll
        for (int mi = 0; mi < 2; ++mi)
#pragma unroll
            for (int r = 0; r < 4; ++r) {
                int a = a0 + mi * 16 + q * 4 + r;
                if (a < N_ATOMS)
#pragma unroll
                    for (int ni = 0; ni < 2; ++ni) {
                        int col = wave * 32 + ni * 16 + c16;
                        pq[a * 512 + col] = (unsigned short)f2bf(pacc[mi][ni][r] + bs1c[ni]);
                    }
            }
    }

    // Q_d = V_d @ w_s1[256:384] (B frags hoisted)
    short8 bq[4][2];
#pragma unroll
    for (int kk = 0; kk < 4; ++kk)
#pragma unroll
        for (int ni = 0; ni < 2; ++ni) {
            int n = wave * 32 + ni * 16 + c16;
            bq[kk][ni] = *(const short8*)&wt[WS1_O + n * 384 + 256 + kk * 32 + q * 8];
        }
#pragma unroll
    for (int d = 0; d < 3; ++d) {
        floatx4 qacc[2][2];
#pragma unroll
        for (int mi = 0; mi < 2; ++mi) { qacc[mi][0] = zero4; qacc[mi][1] = zero4; }
#pragma unroll
        for (int kk = 0; kk < 4; ++kk) {
            short8 af[2];
#pragma unroll
            for (int mi = 0; mi < 2; ++mi)
                af[mi] = *(const short8*)&bufV[(d * 32 + mi * 16 + c16) * 136 + kk * 32 + q * 8];
#pragma unroll
            for (int mi = 0; mi < 2; ++mi)
#pragma unroll
                for (int ni = 0; ni < 2; ++ni)
                    qacc[mi][ni] = MFMA16(af[mi], bq[kk][ni], qacc[mi][ni]);
        }
#pragma unroll
        for (int mi = 0; mi < 2; ++mi)
#pragma unroll
            for (int r = 0; r < 4; ++r) {
                int a = a0 + mi * 16 + q * 4 + r;
                if (a < N_ATOMS)
#pragma unroll
                    for (int ni = 0; ni < 2; ++ni) {
                        int col = wave * 32 + ni * 16 + c16;
                        pq[a * 512 + (1 + d) * 128 + col] = (unsigned short)f2bf(qacc[mi][ni][r]);
                    }
            }
    }
}

__global__ __launch_bounds__(256, 4) void cfr_main(
    const float* __restrict__ diff,
    const int* __restrict__ atom_idx, const int* __restrict__ probe_idx,
    const unsigned short* __restrict__ wt, const unsigned short* __restrict__ pq,
    const float* __restrict__ wtab,
    const float* __restrict__ g_ln, const float* __restrict__ b_ln,
    const float* __restrict__ b_s2, const float* __restrict__ b_o1,
    const float* __restrict__ w_o2, const float* __restrict__ b_o2,
    float* __restrict__ out)
{
    __shared__ __align__(16) unsigned short LDSu[LDS_SH];
    float* mpart = (float*)&LDSu[MPT_O];

    const int t    = threadIdx.x;
    const int e0   = blockIdx.x * EPB;
    const int wave = t >> 6;
    const int lane = t & 63;
    const int q    = lane >> 4;
    const int c16  = lane & 15;
    const floatx4 zero4 = {0.f, 0.f, 0.f, 0.f};

    const int el = t >> 2;             // local edge 0..63 (phase-1 / G-phase mapping)
    const int c0 = (t & 3) * 32;       // this thread's 32-col chunk
    float dist;                        // carried phase1 -> G-phase

    // ---------- phase 1: U = P + r.Q -> LN -> SiLU -> A2 ----------
    {
        const int eg = e0 + el;
        const int a  = atom_idx[eg];
        float dx = diff[eg * 3 + 0], dy = diff[eg * 3 + 1], dz = diff[eg * 3 + 2];
        float sq = dx * dx + dy * dy + dz * dz;
        dist = sqrtf(sq);
        float rinv = rsqrtf(sq + 1e-8f);
        float rx = dx * rinv, ry = dy * rinv, rz = dz * rinv;

        const ushort8* pqr = (const ushort8*)(pq + a * 512 + c0);
        float u[32];
#pragma unroll
        for (int g = 0; g < 4; ++g) {
            ushort8 v = pqr[g];            // P
#pragma unroll
            for (int j = 0; j < 8; ++j) u[g * 8 + j] = bf2f(v[j]);
        }
#pragma unroll
        for (int g = 0; g < 4; ++g) {
            ushort8 v = pqr[16 + g];       // Q0
#pragma unroll
            for (int j = 0; j < 8; ++j) u[g * 8 + j] = fmaf(bf2f(v[j]), rx, u[g * 8 + j]);
        }
#pragma unroll
        for (int g = 0; g < 4; ++g) {
            ushort8 v = pqr[32 + g];       // Q1
#pragma unroll
            for (int j = 0; j < 8; ++j) u[g * 8 + j] = fmaf(bf2f(v[j]), ry, u[g * 8 + j]);
        }
#pragma unroll
        for (int g = 0; g < 4; ++g) {
            ushort8 v = pqr[48 + g];       // Q2
#pragma unroll
            for (int j = 0; j < 8; ++j) u[g * 8 + j] = fmaf(bf2f(v[j]), rz, u[g * 8 + j]);
        }
        float s = 0.f, s2 = 0.f;
#pragma unroll
        for (int j = 0; j < 32; ++j) { s += u[j]; s2 = fmaf(u[j], u[j], s2); }
        s  += __shfl_xor(s, 1);  s  += __shfl_xor(s, 2);
        s2 += __shfl_xor(s2, 1); s2 += __shfl_xor(s2, 2);
        float mu = s * (1.f / 128.f);
        float rstd = rsqrtf(s2 * (1.f / 128.f) - mu * mu + 1e-5f);
        const float4* gp = (const float4*)(g_ln + c0);
        const float4* bp = (const float4*)(b_ln + c0);
        unsigned pko[16];
#pragma unroll
        for (int g4 = 0; g4 < 8; ++g4) {
            float4 gg = gp[g4], bb = bp[g4];
            float y0 = silu_f((u[g4 * 4 + 0] - mu) * rstd * gg.x + bb.x);
            float y1 = silu_f((u[g4 * 4 + 1] - mu) * rstd * gg.y + bb.y);
            float y2 = silu_f((u[g4 * 4 + 2] - mu) * rstd * gg.z + bb.z);
            float y3 = silu_f((u[g4 * 4 + 3] - mu) * rstd * gg.w + bb.w);
            pko[g4 * 2 + 0] = pk2(y0, y1);
            pko[g4 * 2 + 1] = pk2(y2, y3);
        }
        uint4* dst = (uint4*)&LDSu[A2_O + el * ASTR + c0];
        dst[0] = make_uint4(pko[0], pko[1], pko[2], pko[3]);
        dst[1] = make_uint4(pko[4], pko[5], pko[6], pko[7]);
        dst[2] = make_uint4(pko[8], pko[9], pko[10], pko[11]);
        dst[3] = make_uint4(pko[12], pko[13], pko[14], pko[15]);
    }
    __syncthreads();   // A2 ready

    // ---------- mm2: S = A2 @ w_s2 + b_s2 -> bf16 S region (no activation) ----------
    {
        floatx4 sacc[4][2];
#pragma unroll
        for (int mi = 0; mi < 4; ++mi) { sacc[mi][0] = zero4; sacc[mi][1] = zero4; }
#pragma unroll
        for (int kk = 0; kk < 4; ++kk) {
            short8 a2f[4], b2[2];
#pragma unroll
            for (int ni = 0; ni < 2; ++ni) {
                int n = wave * 32 + ni * 16 + c16;
                b2[ni] = *(const short8*)&wt[WS2_O + n * 128 + kk * 32 + q * 8];
            }
#pragma unroll
            for (int mi = 0; mi < 4; ++mi)
                a2f[mi] = *(const short8*)&LDSu[A2_O + (mi * 16 + c16) * ASTR + kk * 32 + q * 8];
#pragma unroll
            for (int mi = 0; mi < 4; ++mi)
#pragma unroll
                for (int ni = 0; ni < 2; ++ni)
                    sacc[mi][ni] = MFMA16(a2f[mi], b2[ni], sacc[mi][ni]);
        }
        float bs2c[2];
#pragma unroll
        for (int ni = 0; ni < 2; ++ni) bs2c[ni] = b_s2[wave * 32 + ni * 16 + c16];
#pragma unroll
        for (int mi = 0; mi < 4; ++mi)
#pragma unroll
            for (int r = 0; r < 4; ++r) {
                int row = mi * 16 + q * 4 + r;
#pragma unroll
                for (int ni = 0; ni < 2; ++ni) {
                    float v = sacc[mi][ni][r] + bs2c[ni];
                    LDSu[S_O + row * ASTR + (wave * 32 + ni * 16 + c16)] =
                        (unsigned short)(__builtin_bit_cast(unsigned, v) >> 16);
                }
            }
    }
    __syncthreads();   // S ready; all A2 reads done

    // ---------- G-phase: G = W(dist) ⊙ S -> A2 region (bf16) ----------
    {
        float f  = fminf(dist * (NTAB / 4.0f), (float)(NTAB - 1));
        float fi = floorf(f);
        int   i0 = (int)fi;
        float fr = f - fi;
        const float* r0 = wtab + i0 * 128 + c0;
        const float* r1 = r0 + 128;
        float w0[32], w1[32];
#pragma unroll
        for (int g4 = 0; g4 < 8; ++g4) {
            *(float4*)&w0[g4 * 4] = *(const float4*)(r0 + g4 * 4);
            *(float4*)&w1[g4 * 4] = *(const float4*)(r1 + g4 * 4);
        }
        ushort8 sv[4];
#pragma unroll
        for (int g = 0; g < 4; ++g)
            sv[g] = *(const ushort8*)&LDSu[S_O + el * ASTR + c0 + g * 8];
        unsigned pko[16];
#pragma unroll
        for (int p = 0; p < 16; ++p) {
            int j0 = p * 2, j1 = p * 2 + 1;
            float wa = fmaf(fr, w1[j0] - w0[j0], w0[j0]);
            float wb = fmaf(fr, w1[j1] - w0[j1], w0[j1]);
            float ga = bf2f(sv[j0 >> 3][j0 & 7]) * wa;
            float gb = bf2f(sv[j1 >> 3][j1 & 7]) * wb;
            pko[p] = pk2(ga, gb);
        }
        uint4* dst = (uint4*)&LDSu[A2_O + el * ASTR + c0];
        dst[0] = make_uint4(pko[0], pko[1], pko[2], pko[3]);
        dst[1] = make_uint4(pko[4], pko[5], pko[6], pko[7]);
        dst[2] = make_uint4(pko[8], pko[9], pko[10], pko[11]);
        dst[3] = make_uint4(pko[12], pko[13], pko[14], pko[15]);
    }
    __syncthreads();   // G ready

    // ---------- head: O1 = G @ w_o1 ; m = silu(O1) @ w_o2 ----------
    {
        const int n2 = wave * 16 + c16;
        floatx4 oacc[4];
#pragma unroll
        for (int mi = 0; mi < 4; ++mi) oacc[mi] = zero4;
#pragma unroll
        for (int kk = 0; kk < 4; ++kk) {
            short8 bfr = *(const short8*)&wt[WO1_O + n2 * 128 + kk * 32 + q * 8];
#pragma unroll
            for (int mi = 0; mi < 4; ++mi) {
                short8 af = *(const short8*)&LDSu[A2_O + (mi * 16 + c16) * ASTR + kk * 32 + q * 8];
                oacc[mi] = MFMA16(af, bfr, oacc[mi]);
            }
        }
        float bo1c = b_o1[n2], wo2c = w_o2[n2];
#pragma unroll
        for (int mi = 0; mi < 4; ++mi)
#pragma unroll
            for (int r = 0; r < 4; ++r) {
                float s = silu_f(oacc[mi][r] + bo1c) * wo2c;
#pragma unroll
                for (int d = 1; d < 16; d <<= 1) s += __shfl_xor(s, d, 64);
                if (c16 == 0) mpart[(mi * 16 + q * 4 + r) * 4 + wave] = s;
            }
    }
    __syncthreads();

    // ---------- envelope + scatter-add ----------
    if (t < EPB) {
        int eg = e0 + t;
        float m = mpart[t * 4 + 0] + mpart[t * 4 + 1] + mpart[t * 4 + 2] + mpart[t * 4 + 3] + b_o2[0];
        float dx = diff[eg * 3 + 0], dy = diff[eg * 3 + 1], dz = diff[eg * 3 + 2];
        float dd = sqrtf(dx * dx + dy * dy + dz * dz);
        float x  = dd * 0.25f;
        float x2 = x * x, x4 = x2 * x2;
        float x5 = x4 * x, x6 = x5 * x, x7 = x6 * x;
        float env = 1.0f - 21.0f * x5 + 35.0f * x6 - 15.0f * x7;
        env = (dd < 4.0f) ? env : 0.0f;
        float mw = m * env;
        if (mw != 0.f) unsafeAtomicAdd(&out[probe_idx[eg]], mw);
    }
}

extern "C" void kernel_launch(void* const* d_in, const int* in_sizes, int n_in,
                              void* d_out, int out_size, void* d_ws, size_t ws_size,
                              hipStream_t stream) {
    const float* diff    = (const float*)d_in[0];
    const float* S_JK    = (const float*)d_in[1];
    const float* V_JK    = (const float*)d_in[2];
    const int*   atom_i  = (const int*)d_in[3];
    const int*   probe_i = (const int*)d_in[4];
    const float* w_s1 = (const float*)d_in[6];
    const float* b_s1 = (const float*)d_in[7];
    const float* g_ln = (const float*)d_in[8];
    const float* b_ln = (const float*)d_in[9];
    const float* w_s2 = (const float*)d_in[10];
    const float* b_s2 = (const float*)d_in[11];
    const float* w_f1 = (const float*)d_in[12];
    const float* b_f1 = (const float*)d_in[13];
    const float* w_f2 = (const float*)d_in[14];
    const float* b_f2 = (const float*)d_in[15];
    const float* w_o1 = (const float*)d_in[16];
    const float* b_o1 = (const float*)d_in[17];
    const float* w_o2 = (const float*)d_in[18];
    const float* b_o2 = (const float*)d_in[19];
    const float* fbias = (const float*)d_in[20];
    float* out = (float*)d_out;

    unsigned short* wt  = (unsigned short*)d_ws;
    unsigned short* pqp = wt + PQ_O;
    float* wtab = (float*)((char*)d_ws + WTAB_OFF_B);   // total ws use ~22.7 MB

    cfr_prep_w<<<(NPROBE + 255) / 256, 256, 0, stream>>>(w_s1, w_s2, w_o1, fbias, out, wt);
    cfr_prep_wtab<<<NTAB + 1, 128, 0, stream>>>(w_f1, b_f1, w_f2, b_f2, wtab);
    cfr_prep_pq<<<(N_ATOMS + 31) / 32, 256, 0, stream>>>(S_JK, V_JK, b_s1, wt, pqp);
    cfr_main<<<E_TOTAL / EPB, 256, 0, stream>>>(diff, atom_i, probe_i, wt, pqp, wtab,
        g_ln, b_ln, b_s2, b_o1, w_o2, b_o2, out);
}